// Round 13
// baseline (161.312 us; speedup 1.0000x reference)
//
#include <hip/hip_runtime.h>
#include <hip/hip_bf16.h>

// B=2, S=2048, H=16, D=64, D_MODEL=1024, M=B*S=4096
// ws layout (bytes):
//   WT  @ 0MB  : [4][1024][1024] bf16 (w_q^T, w_k^T, w_v^T, w_o^T)  8MB
//   Qh  @ 32MB : [32][2048][64]  bf16 (scaled by 0.125*log2e)       8MB
//   Kh  @ 40MB : [32][2048][64]  bf16                               8MB
//   Vt  @ 48MB : [32][64][2048]  bf16 (per-head transposed V)       8MB
//   Ob  @ 56MB : [4096][1024]    bf16 (attention output)            8MB

using bf16x8 = __attribute__((ext_vector_type(8))) short;
using f32x4  = __attribute__((ext_vector_type(4))) float;
using u32x4  = __attribute__((ext_vector_type(4))) unsigned;
typedef unsigned short u16;
using u16x4 = __attribute__((ext_vector_type(4))) u16;
using u16x8 = __attribute__((ext_vector_type(8))) u16;

#define GLDS16(g, l) __builtin_amdgcn_global_load_lds( \
    (const __attribute__((address_space(1))) void*)(g), \
    (__attribute__((address_space(3))) void*)(l), 16, 0, 0)

#if __has_builtin(__builtin_amdgcn_exp2f)
#define EXP2(x) __builtin_amdgcn_exp2f(x)
#else
#define EXP2(x) exp2f(x)
#endif

// Raw s_barrier is IntrNoMem: pair it with compiler memory fences so LDS
// reads/writes cannot be moved across it at compile time.
__device__ __forceinline__ void block_sync() {
  __builtin_amdgcn_sched_barrier(0);
  asm volatile("" ::: "memory");
  __builtin_amdgcn_s_barrier();
  asm volatile("" ::: "memory");
  __builtin_amdgcn_sched_barrier(0);
}

__device__ __forceinline__ u16 f2bf(float f) {
  unsigned u = __builtin_bit_cast(unsigned, f);
  u += 0x7fffu + ((u >> 16) & 1u);
  return (u16)(u >> 16);
}

// packed f32->bf16 RNE (no builtin on gfx950; T12 primitive)
__device__ __forceinline__ unsigned cvt_pk_bf16(float lo, float hi) {
  unsigned r;
  asm("v_cvt_pk_bf16_f32 %0, %1, %2" : "=v"(r) : "v"(lo), "v"(hi));
  return r;
}

__device__ __forceinline__ float fmax3(float a, float b, float c) {
  return fmaxf(fmaxf(a, b), c);  // clang fuses to v_max3_f32
}

// ---------- kernel 1: weight transpose+convert: WT[z][n][k] = bf16(w_z[k][n]) ----------
__global__ __launch_bounds__(256) void wtrans_kernel(
    const float* __restrict__ wq, const float* __restrict__ wk,
    const float* __restrict__ wv, const float* __restrict__ wo,
    u16* __restrict__ dst) {
  __shared__ float t[32][33];
  const int z = blockIdx.z;
  const float* src = (z == 0) ? wq : (z == 1) ? wk : (z == 2) ? wv : wo;
  u16* d = dst + (size_t)z * 1024 * 1024;
  const int tx = threadIdx.x & 31, ty = threadIdx.x >> 5;
  const int bx = blockIdx.x * 32, by = blockIdx.y * 32;
#pragma unroll
  for (int j = 0; j < 4; j++)
    t[ty + j * 8][tx] = src[(size_t)(by + ty + j * 8) * 1024 + bx + tx];
  __syncthreads();
#pragma unroll
  for (int j = 0; j < 4; j++)
    d[(size_t)(bx + ty + j * 8) * 1024 + by + tx] = f2bf(t[tx][ty + j * 8]);
}

// ---------- kernel 2: fused QKV projections (2-deep pipelined, XCD-chunked) ----------
// 768 blocks 1-D; xcd=id&7 owns y-panels [4*xcd,4*xcd+4) x all 8 bcols per z.
// In-order vmcnt queue per step k: [A[k], B[k], A[k+1]] (20 outstanding).
//   pre-wait vmcnt(12)  -> drains A[k] (CVT safe)
//   issue B[k+1](4), A[k+2](8) -> 24 outstanding
//   WRITEA; wait vmcnt(20) lgkmcnt(0) -> drains B[k]; A gets 2 steps of cover.
// Q/K epilogue: LDS-transpose -> u16x8 stores (1KB contiguous per wave) to
// kill the 2x write amplification seen in R12 (WRITE_SIZE 47.6MB for 24MB).
__global__ __launch_bounds__(256, 3) void proj_kernel(
    const float* __restrict__ qf, const float* __restrict__ kf,
    const float* __restrict__ vf, const u16* __restrict__ WT,
    u16* __restrict__ Qh, u16* __restrict__ Kh, u16* __restrict__ Vt) {
  __shared__ u16 lds[24576];     // [0,8192): A; [8192,16384): B0; [16384,24576): B1
  const int id = blockIdx.x;
  const int xcd = id & 7, l = id >> 3;      // l in [0,96)
  const int z = l >> 5, rem = l & 31;       // 32 blocks per XCD per z
  const int by = xcd * 4 + (rem >> 3);      // 4 y-panels per XCD
  const int bx = rem & 7;
  const int arow0 = by * 128, bcol0 = bx * 128;
  const float* A = (z == 0) ? qf : (z == 1) ? kf : vf;
  const u16* Bw = WT + (size_t)z * 1024 * 1024;

  const int tid = threadIdx.x;
  const int lane = tid & 63, wave = tid >> 6;
  const int lr = lane & 15, lg = lane >> 4;
  const int wr = (wave >> 1) * 64, wc = (wave & 1) * 64;
  const int ar = tid >> 3, ac = tid & 7;    // A stage: row base, chunk
  f32x4 acc[4][4] = {};

  f32x4 fa[2][4][2];   // 2-deep in-flight A fp32 regs (8 loads/tile each)
  u32x4 w[4];          // packed bf16 A (consumed by ds_write)

  auto LOADA = [&](int kt, int p) {
#pragma unroll
    for (int i = 0; i < 4; i++) {
      const float* ap = A + (size_t)(arow0 + i * 32 + ar) * 1024 + kt + ac * 8;
      fa[p][i][0] = *(const f32x4*)ap;
      fa[p][i][1] = *(const f32x4*)(ap + 4);
    }
  };
  auto GLDSB = [&](int kt, int nb) {
    u16* bd = lds + 8192 + nb * 8192;
#pragma unroll
    for (int i = 0; i < 4; i++) {
      int o = (i * 256 + tid) * 8;
      int row = o >> 6, ch = (o >> 3) & 7;
      int sc = (ch ^ (row & 7)) << 3;
      GLDS16(Bw + (size_t)(bcol0 + row) * 1024 + kt + sc, bd + o);
    }
  };
  auto CVT = [&](int p) {
#pragma unroll
    for (int i = 0; i < 4; i++) {
      u32x4 v = {cvt_pk_bf16(fa[p][i][0][0], fa[p][i][0][1]),
                 cvt_pk_bf16(fa[p][i][0][2], fa[p][i][0][3]),
                 cvt_pk_bf16(fa[p][i][1][0], fa[p][i][1][1]),
                 cvt_pk_bf16(fa[p][i][1][2], fa[p][i][1][3])};
      w[i] = v;
    }
  };
  auto WRITEA = [&]() {
#pragma unroll
    for (int i = 0; i < 4; i++) {
      int row = i * 32 + ar;
      *(u32x4*)&lds[row * 64 + ((ac ^ (row & 7)) << 3)] = w[i];
    }
  };
  auto MFMAK = [&](int cb) {
    const u16* Bb = lds + 8192 + cb * 8192;
#pragma unroll
    for (int kk = 0; kk < 2; kk++) {
      bf16x8 af[4], bfr[4];
      const int ke = kk * 32 + lg * 8;
#pragma unroll
      for (int m = 0; m < 4; m++) {
        int row = wr + m * 16 + lr;
        af[m] = *(const bf16x8*)&lds[row * 64 + (ke ^ ((row & 7) << 3))];
      }
#pragma unroll
      for (int n = 0; n < 4; n++) {
        int row = wc + n * 16 + lr;
        bfr[n] = *(const bf16x8*)&Bb[row * 64 + (ke ^ ((row & 7) << 3))];
      }
#pragma unroll
      for (int m = 0; m < 4; m++)
#pragma unroll
        for (int n = 0; n < 4; n++)
          acc[m][n] = __builtin_amdgcn_mfma_f32_16x16x32_bf16(af[m], bfr[n],
                                                              acc[m][n], 0, 0, 0);
    }
  };

// MODE 0: steady (issue B[k+1]+A[k+2]); 1: issue B[k+1] only; 2: drain
#define PSTEP(KT, CB, P, MODE)                                               \
  do {                                                                       \
    if (MODE == 2)                                                           \
      asm volatile("s_waitcnt vmcnt(4)" ::: "memory");                       \
    else                                                                     \
      asm volatile("s_waitcnt vmcnt(12)" ::: "memory");                      \
    CVT(P);                                                                  \
    if (MODE <= 1) GLDSB((KT) + 64, (CB) ^ 1);                               \
    if (MODE == 0) LOADA((KT) + 128, P);                                     \
    WRITEA();                                                                \
    if (MODE == 0)                                                           \
      asm volatile("s_waitcnt vmcnt(20) lgkmcnt(0)" ::: "memory");           \
    else if (MODE == 1)                                                      \
      asm volatile("s_waitcnt vmcnt(12) lgkmcnt(0)" ::: "memory");           \
    else                                                                     \
      asm volatile("s_waitcnt vmcnt(0) lgkmcnt(0)" ::: "memory");            \
    block_sync();                                                            \
    MFMAK(CB);                                                               \
    block_sync();                                                            \
  } while (0)

  LOADA(0, 0);     // A[0]
  GLDSB(0, 0);     // B[0]
  LOADA(64, 1);    // A[1]  -> queue: [A0(8), B0(4), A1(8)]
  for (int kt = 0; kt < 896; kt += 128) {   // tiles 0..13
    PSTEP(kt, 0, 0, 0);
    PSTEP(kt + 64, 1, 1, 0);
  }
  PSTEP(896, 0, 0, 1);   // tile 14: issue B[15] only
  PSTEP(960, 1, 1, 2);   // tile 15: drain
#undef PSTEP

  if (z == 2) {
    // V: transpose through LDS -> Vt[(b*16+h)*64+d][s]
    u16* T = lds;  // [128 c][128 s], swizzled rows (32KB of the 48KB)
    __syncthreads();
#pragma unroll
    for (int m = 0; m < 4; m++)
#pragma unroll
      for (int n = 0; n < 4; n++)
#pragma unroll
        for (int r = 0; r < 4; r++) {
          int sl = wr + m * 16 + lg * 4 + r;
          int cl = wc + n * 16 + lr;
          T[cl * 128 + (sl ^ ((cl & 7) << 3))] = f2bf(acc[m][n][r]);
        }
    __syncthreads();
    const int t = threadIdx.x;
    const int cl = t >> 1, s0 = (t & 1) * 64;
    const int gc = bcol0 + cl;
    const size_t vrow = ((size_t)(arow0 >> 11) * 16 + (gc >> 6)) * 64 + (gc & 63);
#pragma unroll
    for (int j = 0; j < 8; j++) {
      int sl = s0 + j * 8;
      u16x8 vv = *(const u16x8*)&T[cl * 128 + (sl ^ ((cl & 7) << 3))];
      *(u16x8*)&Vt[vrow * 2048 + (size_t)((arow0 & 2047) + sl)] = vv;
    }
  } else {
    // Q/K: LDS transpose T[s][c] -> vectorized u16x8 stores (1KB/wave rows)
    const float scale = (z == 0) ? 0.18033688f : 1.0f;  // 0.125 * log2(e)
    u16* dst = (z == 0) ? Qh : Kh;
    u16* T = lds;  // [128 s][128 c], swizzled
    __syncthreads();
#pragma unroll
    for (int m = 0; m < 4; m++)
#pragma unroll
      for (int n = 0; n < 4; n++)
#pragma unroll
        for (int r = 0; r < 4; r++) {
          int sl = wr + m * 16 + lg * 4 + r;
          int cl = wc + n * 16 + lr;
          T[sl * 128 + (cl ^ ((sl & 7) << 3))] = f2bf(acc[m][n][r] * scale);
        }
    __syncthreads();
    const int t = threadIdx.x;
    const int h2 = t >> 7, tt = t & 127;
    const int rb = tt >> 3, c0 = (tt & 7) * 8;
    const size_t bh = (size_t)(arow0 >> 11) * 16 + bx * 2 + h2;
#pragma unroll
    for (int j = 0; j < 8; j++) {
      int row = j * 16 + rb;
      int cl = h2 * 64 + c0;
      u16x8 vv = *(const u16x8*)&T[row * 128 + (cl ^ ((row & 7) << 3))];
      *(u16x8*)&dst[(bh * 2048 + (size_t)((arow0 & 2047) + row)) * 64 + c0] = vv;
    }
  }
}

// ---------- kernel 3: flash attention (swapped QK^T, P in registers) ----------
// 512 blocks (XCD-swizzled) x 8 waves, 128 q-rows per block, 16 per wave.
// Quad-buffered K/V (64KB LDS), 2-deep prefetch, steady vmcnt(6);
// launch_bounds(512,4) -> 2 blocks/CU = 16 waves/CU, grid exactly resident.
// S^T = mfma(K-frag, Q-frag): lane owns q = lane&15; K rows fed through
// permutation κ(n,a)=32(n>>1)+8(a>>2)+4(n&1)+(a&3) so the lane's 16 keys are
// exactly the PV A-fragment sets {8*lg..+7} u {32+8*lg..+7} -> zero exchange.
// K bank swizzle h(kr)=(kr&3)|(((kr>>3)&1)<<2): bijective on bank-groups for
// every 8 consecutive lanes.
__global__ __launch_bounds__(512, 4) void attn_kernel(
    const u16* __restrict__ Qh, const u16* __restrict__ Kh,
    const u16* __restrict__ Vt, u16* __restrict__ Ob) {
  __shared__ u16 kt[4][64 * 64];  // K tiles [key][d], h-swizzled rows
  __shared__ u16 vt[4][64 * 64];  // V^T tiles [d][s], xor-swizzled rows
  const int tid = threadIdx.x;
  const int lane = tid & 63, wave = tid >> 6;
  const int lr = lane & 15, lg = lane >> 4;
  // bijective XCD swizzle (512 % 8 == 0): each XCD owns 4 complete bh's
  const int id = blockIdx.x;
  const int swz = (id & 7) * 64 + (id >> 3);
  const int bh = swz >> 4;
  const int q0 = (swz & 15) * 128;
  const u16* Qb = Qh + ((size_t)bh * 2048 + q0) * 64;
  const u16* Kb = Kh + (size_t)bh * 2048 * 64;
  const u16* Vb = Vt + (size_t)bh * 64 * 2048;

  // Q fragment (B-operand of swapped QK^T); wave owns q-rows [wave*16, +16)
  bf16x8 aq[2];
#pragma unroll
  for (int kk = 0; kk < 2; kk++)
    aq[kk] = *(const bf16x8*)(Qb + (wave * 16 + lr) * 64 + kk * 32 + lg * 8);

  // K A-operand LDS offsets: perm κ, swizzle h (h depends only on lr)
  const int hsw = (lr & 3) | (((lr >> 2) & 1) << 2);
  int koff[2][4];
#pragma unroll
  for (int n = 0; n < 4; n++) {
    int kr = 32 * (n >> 1) + 8 * (lr >> 2) + 4 * (n & 1) + (lr & 3);
#pragma unroll
    for (int kk = 0; kk < 2; kk++)
      koff[kk][n] = kr * 64 + ((kk * 32 + lg * 8) ^ (hsw << 3));
  }
  // V B-operand LDS offsets
  int voff[2][4];
#pragma unroll
  for (int n = 0; n < 4; n++) {
    int d = n * 16 + lr;
#pragma unroll
    for (int ks = 0; ks < 2; ks++)
      voff[ks][n] = d * 64 + ((ks * 32 + lg * 8) ^ ((d & 7) << 3));
  }

  // staging: 512 threads cover one 64x64 K tile + one 64x64 V tile,
  // 1 chunk of 16B each; row = tid>>3, ch = tid&7
  const int o0 = tid * 8;
  const int srow = tid >> 3, sch = tid & 7;
  const int hk = (srow & 3) | (((srow >> 3) & 1) << 2);
  const u16* kg = Kb + (size_t)srow * 64 + ((sch ^ hk) << 3);
  const u16* vg = Vb + (size_t)srow * 2048 + ((sch ^ (srow & 7)) << 3);

  f32x4 oacc[4] = {};
  float mrun = -1e30f, lrun = 0.f;

  auto STAGE = [&](int t, int b) {  // b literal at call site; 2 insts/thread
    GLDS16(kg + (size_t)t * 4096, &kt[0][0] + b * 4096 + o0);
    GLDS16(vg + t * 64, &vt[0][0] + b * 4096 + o0);
  };

  auto COMPUTE = [&](int cur) {  // cur literal at call site
    // S^T tile: sacc[n][r] = S[key κ(n, lg*4+r)][q=lr] (log2 domain)
    f32x4 sacc[4] = {};
    __builtin_amdgcn_s_setprio(1);
#pragma unroll
    for (int kk = 0; kk < 2; kk++) {
#pragma unroll
      for (int n = 0; n < 4; n++) {
        bf16x8 ka = *(const bf16x8*)&kt[cur][koff[kk][n]];
        sacc[n] = __builtin_amdgcn_mfma_f32_16x16x32_bf16(ka, aq[kk],
                                                          sacc[n], 0, 0, 0);
      }
    }
    __builtin_amdgcn_s_setprio(0);
    // row max: 7 max3 + 1 fmax in-lane, then 2 cross-lane steps
    float t0 = fmax3(sacc[0][0], sacc[0][1], sacc[0][2]);
    float t1 = fmax3(sacc[0][3], sacc[1][0], sacc[1][1]);
    float t2 = fmax3(sacc[1][2], sacc[1][3], sacc[2][0]);
    float t3 = fmax3(sacc[2][1], sacc[2][2], sacc[2][3]);
    float t4 = fmax3(sacc[3][0], sacc[3][1], sacc[3][2]);
    float mx = fmaxf(fmax3(t0, t1, t2), fmax3(t3, t4, sacc[3][3]));
    mx = fmaxf(mx, __shfl_xor(mx, 16));
    mx = fmaxf(mx, __shfl_xor(mx, 32));
    float mnew = fmaxf(mrun, mx);
    // defer-max (T13): skip rescale when growth <= 8 (log2 domain -> p <= 256)
    if (__all(mx - mrun <= 8.0f)) {
      mnew = mrun;
    } else {
      float corr = EXP2(mrun - mnew);
      mrun = mnew;
      lrun *= corr;
      float cr[4];
#pragma unroll
      for (int r = 0; r < 4; r++) cr[r] = __shfl(corr, lg * 4 + r);
#pragma unroll
      for (int n = 0; n < 4; n++)
#pragma unroll
        for (int r = 0; r < 4; r++) oacc[n][r] *= cr[r];
    }
    // p = exp2(s - m), in place; row-sum
    float psum = 0.f;
#pragma unroll
    for (int n = 0; n < 4; n++)
#pragma unroll
      for (int r = 0; r < 4; r++) {
        float p = EXP2(sacc[n][r] - mnew);
        sacc[n][r] = p;
        psum += p;
      }
    psum += __shfl_xor(psum, 16);
    psum += __shfl_xor(psum, 32);
    lrun += psum;
    // pack P into PV A-fragments via v_cvt_pk_bf16_f32
    u32x4 w0 = {cvt_pk_bf16(sacc[0][0], sacc[0][1]),
                cvt_pk_bf16(sacc[0][2], sacc[0][3]),
                cvt_pk_bf16(sacc[1][0], sacc[1][1]),
                cvt_pk_bf16(sacc[1][2], sacc[1][3])};
    u32x4 w1 = {cvt_pk_bf16(sacc[2][0], sacc[2][1]),
                cvt_pk_bf16(sacc[2][2], sacc[2][3]),
                cvt_pk_bf16(sacc[3][0], sacc[3][1]),
                cvt_pk_bf16(sacc[3][2], sacc[3][3])};
    bf16x8 pa0 = __builtin_bit_cast(bf16x8, w0);
    bf16x8 pa1 = __builtin_bit_cast(bf16x8, w1);
    // O += P V
    __builtin_amdgcn_s_setprio(1);
#pragma unroll
    for (int ks = 0; ks < 2; ks++) {
      bf16x8 ap = ks ? pa1 : pa0;
      bf16x8 bv[4];
#pragma unroll
      for (int n = 0; n < 4; n++)
        bv[n] = *(const bf16x8*)&vt[cur][voff[ks][n]];
#pragma unroll
      for (int n = 0; n < 4; n++)
        oacc[n] = __builtin_amdgcn_mfma_f32_16x16x32_bf16(ap, bv[n],
                                                          oacc[n], 0, 0, 0);
    }
    __builtin_amdgcn_s_setprio(0);
  };

#define VMC6 asm volatile("s_waitcnt vmcnt(6)" ::: "memory")
#define VMC4 asm volatile("s_waitcnt vmcnt(4)" ::: "memory")
#define VMC2 asm volatile("s_waitcnt vmcnt(2)" ::: "memory")
#define VMC0 asm volatile("s_waitcnt vmcnt(0)" ::: "memory")
  STAGE(0, 0); STAGE(1, 1); STAGE(2, 2);
  // quad-buffered, 2 tiles in flight; unrolled x4 so buf indices are literals
  for (int t = 0; t < 28; t += 4) {
    STAGE(t + 3, 3); VMC6; block_sync(); COMPUTE(0); block_sync();
    STAGE(t + 4, 0); VMC6; block_sync(); COMPUTE(1); block_sync();
    STAGE(t + 5, 1); VMC6; block_sync(); COMPUTE(2); block_sync();
    STAGE(t + 6, 2); VMC6; block_sync(); COMPUTE(3); block_sync();
  }
  // staged 0..30, computed 0..27
  STAGE(31, 3); VMC6; block_sync(); COMPUTE(0); block_sync();  // tile 28
  VMC4; block_sync(); COMPUTE(1); block_sync();                // tile 29
  VMC2; block_sync(); COMPUTE(2); block_sync();                // tile 30
  VMC0; block_sync(); COMPUTE(3);                              // tile 31
#undef VMC6
#undef VMC4
#undef VMC2
#undef VMC0

  // epilogue: normalize (inv lives at q=lr; oacc rows are q=lg*4+r)
  const int b = bh >> 4, h = bh & 15;
  float inv = 1.0f / lrun;
  float ivr[4];
#pragma unroll
  for (int r = 0; r < 4; r++) ivr[r] = __shfl(inv, lg * 4 + r);
#pragma unroll
  for (int r = 0; r < 4; r++) {
    int qrow = q0 + wave * 16 + lg * 4 + r;
#pragma unroll
    for (int n = 0; n < 4; n++) {
      int d = n * 16 + lr;
      Ob[((size_t)b * 2048 + qrow) * 1024 + h * 64 + d] = f2bf(oacc[n][r] * ivr[r]);
    }
  }
}

// ---------- kernel 4: output projection (128x64 tile, XCD-chunked 512 blocks) ----------
__global__ __launch_bounds__(256) void outproj_kernel(
    const u16* __restrict__ Ob, const u16* __restrict__ WoT,
    float* __restrict__ out) {
  __shared__ u16 ldsA[128 * 64];  // 16KB, swizzled rows
  __shared__ u16 ldsB[64 * 64];   //  8KB, swizzled rows
  const int tid = threadIdx.x;
  const int lane = tid & 63, wave = tid >> 6;
  const int lr = lane & 15, lg = lane >> 4;
  const int wr = (wave >> 1) * 64;  // M offset (0/64)
  const int wc = (wave & 1) * 32;   // N offset (0/32)
  // XCD-chunked: xcd owns 4 y-panels x all 16 x -> each A panel one XCD
  const int id = blockIdx.x;
  const int xcd = id & 7, l = id >> 3;   // l in [0,64)
  const int by = xcd * 4 + (l >> 4);     // 0..31
  const int bx = l & 15;                 // 0..15
  const int arow0 = by * 128, bcol0 = bx * 64;
  f32x4 acc[4][2] = {};
  for (int kt = 0; kt < 1024; kt += 64) {
#pragma unroll
    for (int i = 0; i < 4; i++) {
      int o = (i * 256 + tid) * 8;
      int row = o >> 6, ch = (o >> 3) & 7;
      int sc = (ch ^ (row & 7)) << 3;
      GLDS16(Ob + (size_t)(arow0 + row) * 1024 + kt + sc, &ldsA[o]);
    }
#pragma unroll
    for (int i = 0; i < 2; i++) {
      int o = (i * 256 + tid) * 8;
      int row = o >> 6, ch = (o >> 3) & 7;
      int sc = (ch ^ (row & 7)) << 3;
      GLDS16(WoT + (size_t)(bcol0 + row) * 1024 + kt + sc, &ldsB[o]);
    }
    __syncthreads();
#pragma unroll
    for (int kk = 0; kk < 2; kk++) {
      const int ke = kk * 32 + lg * 8;
      bf16x8 af[4], bfr[2];
#pragma unroll
      for (int m = 0; m < 4; m++) {
        int row = wr + m * 16 + lr;
        af[m] = *(const bf16x8*)&ldsA[row * 64 + (ke ^ ((row & 7) << 3))];
      }
#pragma unroll
      for (int n = 0; n < 2; n++) {
        int row = wc + n * 16 + lr;
        bfr[n] = *(const bf16x8*)&ldsB[row * 64 + (ke ^ ((row & 7) << 3))];
      }
#pragma unroll
      for (int m = 0; m < 4; m++)
#pragma unroll
        for (int n = 0; n < 2; n++)
          acc[m][n] = __builtin_amdgcn_mfma_f32_16x16x32_bf16(af[m], bfr[n],
                                                              acc[m][n], 0, 0, 0);
    }
    __syncthreads();
  }
#pragma unroll
  for (int m = 0; m < 4; m++)
#pragma unroll
    for (int n = 0; n < 2; n++)
#pragma unroll
      for (int r = 0; r < 4; r++) {
        int gr = arow0 + wr + m * 16 + lg * 4 + r;
        int gc = bcol0 + wc + n * 16 + lr;
        out[(size_t)gr * 1024 + gc] = acc[m][n][r];
      }
}

extern "C" void kernel_launch(void* const* d_in, const int* in_sizes, int n_in,
                              void* d_out, int out_size, void* d_ws, size_t ws_size,
                              hipStream_t stream) {
  const float* q  = (const float*)d_in[0];
  const float* k  = (const float*)d_in[1];
  const float* v  = (const float*)d_in[2];
  const float* wq = (const float*)d_in[3];
  const float* wk = (const float*)d_in[4];
  const float* wv = (const float*)d_in[5];
  const float* wo = (const float*)d_in[6];
  float* out = (float*)d_out;
  char* ws = (char*)d_ws;

  u16* WT = (u16*)ws;                                    // [4][1024][1024]
  u16* Qh = (u16*)(ws + (size_t)32 * 1024 * 1024);       // [32][2048][64]
  u16* Kh = (u16*)(ws + (size_t)40 * 1024 * 1024);       // [32][2048][64]
  u16* Vt = (u16*)(ws + (size_t)48 * 1024 * 1024);       // [32][64][2048]
  u16* Ob = (u16*)(ws + (size_t)56 * 1024 * 1024);       // [4096][1024]

  wtrans_kernel<<<dim3(32, 32, 4), 256, 0, stream>>>(wq, wk, wv, wo, WT);
  proj_kernel<<<dim3(768), 256, 0, stream>>>(q, k, v, WT, Qh, Kh, Vt);
  attn_kernel<<<dim3(512), 512, 0, stream>>>(Qh, Kh, Vt, Ob);
  outproj_kernel<<<dim3(512), 256, 0, stream>>>(Ob, WT + (size_t)3 * 1024 * 1024, out);
}

// Round 15
// 133.616 us; speedup vs baseline: 1.2073x; 1.2073x over previous
//
#include <hip/hip_runtime.h>
#include <hip/hip_bf16.h>

// B=2, S=2048, H=16, D=64, D_MODEL=1024, M=B*S=4096
// ws layout (bytes):
//   WT  @ 0MB  : [4][1024][1024] bf16 (w_q^T, w_k^T, w_v^T, w_o^T)  8MB
//   Qh  @ 32MB : [32][2048][64]  bf16 (scaled by 0.125*log2e)       8MB
//   Kh  @ 40MB : [32][2048][64]  bf16                               8MB
//   Vt  @ 48MB : [32][64][2048]  bf16 (per-head transposed V)       8MB
//   Ob  @ 56MB : [4096][1024]    bf16 (attention output)            8MB

using bf16x8 = __attribute__((ext_vector_type(8))) short;
using f32x4  = __attribute__((ext_vector_type(4))) float;
using u32x4  = __attribute__((ext_vector_type(4))) unsigned;
using u32x2  = __attribute__((ext_vector_type(2))) unsigned;
typedef unsigned short u16;
using u16x8 = __attribute__((ext_vector_type(8))) u16;

#define GLDS16(g, l) __builtin_amdgcn_global_load_lds( \
    (const __attribute__((address_space(1))) void*)(g), \
    (__attribute__((address_space(3))) void*)(l), 16, 0, 0)

#if __has_builtin(__builtin_amdgcn_exp2f)
#define EXP2(x) __builtin_amdgcn_exp2f(x)
#else
#define EXP2(x) exp2f(x)
#endif

// Raw s_barrier is IntrNoMem: pair it with compiler memory fences so LDS
// reads/writes cannot be moved across it at compile time.
__device__ __forceinline__ void block_sync() {
  __builtin_amdgcn_sched_barrier(0);
  asm volatile("" ::: "memory");
  __builtin_amdgcn_s_barrier();
  asm volatile("" ::: "memory");
  __builtin_amdgcn_sched_barrier(0);
}

__device__ __forceinline__ u16 f2bf(float f) {
  unsigned u = __builtin_bit_cast(unsigned, f);
  u += 0x7fffu + ((u >> 16) & 1u);
  return (u16)(u >> 16);
}

// packed f32->bf16 RNE (no builtin on gfx950; T12 primitive)
__device__ __forceinline__ unsigned cvt_pk_bf16(float lo, float hi) {
  unsigned r;
  asm("v_cvt_pk_bf16_f32 %0, %1, %2" : "=v"(r) : "v"(lo), "v"(hi));
  return r;
}

__device__ __forceinline__ float fmax3(float a, float b, float c) {
  return fmaxf(fmaxf(a, b), c);  // clang fuses to v_max3_f32
}

// ---------- kernel 1: weight transpose+convert: WT[z][n][k] = bf16(w_z[k][n]) ----------
__global__ __launch_bounds__(256) void wtrans_kernel(
    const float* __restrict__ wq, const float* __restrict__ wk,
    const float* __restrict__ wv, const float* __restrict__ wo,
    u16* __restrict__ dst) {
  __shared__ float t[32][33];
  const int z = blockIdx.z;
  const float* src = (z == 0) ? wq : (z == 1) ? wk : (z == 2) ? wv : wo;
  u16* d = dst + (size_t)z * 1024 * 1024;
  const int tx = threadIdx.x & 31, ty = threadIdx.x >> 5;
  const int bx = blockIdx.x * 32, by = blockIdx.y * 32;
#pragma unroll
  for (int j = 0; j < 4; j++)
    t[ty + j * 8][tx] = src[(size_t)(by + ty + j * 8) * 1024 + bx + tx];
  __syncthreads();
#pragma unroll
  for (int j = 0; j < 4; j++)
    d[(size_t)(bx + ty + j * 8) * 1024 + by + tx] = f2bf(t[tx][ty + j * 8]);
}

// ---------- kernel 2: fused QKV projections (64x64 tiles, 6 blocks/CU TLP) ----------
// R13 lesson: register pipelines spill -> hide HBM latency with OCCUPANCY.
// R14 bug fixed here: WRITEA (cvt+ds_write of tile k's fa) must run BEFORE
// LOADA overwrites fa with tile k+1 (R14 had LOADA first -> wrong-tile MFMA).
// 64x64 tile: acc 16 + fa 16 VGPRs, LDS 24KB -> 6 blocks/CU, grid 3072 =
// 2 full-residency rounds, 24 waves/CU TLP.
// XCD-chunked: xcd=id&7 owns [z][8 ypanels][16 bx] -> A panels read by 1 XCD.
// vmcnt queue per step: [A[k](4), B[k](2)]; entry vmcnt(2) drains A[k];
// after issuing A[k+1]+B[k+1]: vmcnt(6) drains B[k], 6 stay in flight.
__global__ __launch_bounds__(256, 6) void proj_kernel(
    const float* __restrict__ qf, const float* __restrict__ kf,
    const float* __restrict__ vf, const u16* __restrict__ WT,
    u16* __restrict__ Qh, u16* __restrict__ Kh, u16* __restrict__ Vt) {
  __shared__ u16 lds[12288];   // [0,4096): A; [4096,8192): B0; [8192,12288): B1
  const int id = blockIdx.x;
  const int xcd = id & 7, r0 = id >> 3;     // r0 in [0,384)
  const int z = r0 >> 7, rem = r0 & 127;    // 128 blocks per XCD per z
  const int yp = xcd * 8 + (rem >> 4);      // 8 y-panels (64 rows) per XCD
  const int bx = rem & 15;                  // 16 col-panels (64 cols)
  const int arow0 = yp * 64, bcol0 = bx * 64;
  const float* A = (z == 0) ? qf : (z == 1) ? kf : vf;
  const u16* Bw = WT + (size_t)z * 1024 * 1024;

  const int tid = threadIdx.x;
  const int lane = tid & 63, wave = tid >> 6;
  const int lr = lane & 15, lg = lane >> 4;
  const int wr = (wave >> 1) * 32, wc = (wave & 1) * 32;
  const int ar = tid >> 2, ac0 = (tid & 3) * 16;   // A stage: row, col base
  f32x4 acc[2][2] = {};
  f32x4 fa[4];     // 16 VGPRs of in-flight A (one 64x64 fp32 tile / thread)

  auto LOADA = [&](int kt) {
    const float* ap = A + (size_t)(arow0 + ar) * 1024 + kt + ac0;
#pragma unroll
    for (int j = 0; j < 4; j++) fa[j] = *(const f32x4*)(ap + 4 * j);
  };
  auto GLDSB = [&](int kt, int nb) {
    u16* bd = lds + 4096 + nb * 4096;
#pragma unroll
    for (int i = 0; i < 2; i++) {
      int o = (i * 256 + tid) * 8;
      int row = o >> 6, ch = (o >> 3) & 7;
      GLDS16(Bw + (size_t)(bcol0 + row) * 1024 + kt + ((ch ^ (row & 7)) << 3),
             bd + o);
    }
  };
  auto WRITEA = [&]() {
    // chunk at ac0 (fa[0],fa[1]) and chunk at ac0+8 (fa[2],fa[3])
    u32x2 c0 = {cvt_pk_bf16(fa[0][0], fa[0][1]), cvt_pk_bf16(fa[0][2], fa[0][3])};
    u32x2 c1 = {cvt_pk_bf16(fa[1][0], fa[1][1]), cvt_pk_bf16(fa[1][2], fa[1][3])};
    u32x2 c2 = {cvt_pk_bf16(fa[2][0], fa[2][1]), cvt_pk_bf16(fa[2][2], fa[2][3])};
    u32x2 c3 = {cvt_pk_bf16(fa[3][0], fa[3][1]), cvt_pk_bf16(fa[3][2], fa[3][3])};
    u32x4 lo = {c0[0], c0[1], c1[0], c1[1]};   // cols ac0..ac0+7
    u32x4 hi = {c2[0], c2[1], c3[0], c3[1]};   // cols ac0+8..ac0+15
    const int swz = (ar & 7) << 3;
    *(u32x4*)&lds[ar * 64 + (ac0 ^ swz)] = lo;
    *(u32x4*)&lds[ar * 64 + ((ac0 + 8) ^ swz)] = hi;
  };
  auto MFMAK = [&](int cb) {
    const u16* Bb = lds + 4096 + cb * 4096;
#pragma unroll
    for (int kk = 0; kk < 2; kk++) {
      const int ke = kk * 32 + lg * 8;
      bf16x8 af[2], bfr[2];
#pragma unroll
      for (int m = 0; m < 2; m++) {
        int row = wr + m * 16 + lr;
        af[m] = *(const bf16x8*)&lds[row * 64 + (ke ^ ((row & 7) << 3))];
      }
#pragma unroll
      for (int n = 0; n < 2; n++) {
        int row = wc + n * 16 + lr;
        bfr[n] = *(const bf16x8*)&Bb[row * 64 + (ke ^ ((row & 7) << 3))];
      }
#pragma unroll
      for (int m = 0; m < 2; m++)
#pragma unroll
        for (int n = 0; n < 2; n++)
          acc[m][n] = __builtin_amdgcn_mfma_f32_16x16x32_bf16(af[m], bfr[n],
                                                              acc[m][n], 0, 0, 0);
    }
  };

  // queue at step entry: [A[k](4), B[k](2)]
#define STEPF(KT, CB)                                                        \
  do {                                                                       \
    asm volatile("s_waitcnt vmcnt(2)" ::: "memory");  /* A[k] landed */      \
    WRITEA();                          /* consume fa BEFORE reload (R14!) */ \
    LOADA((KT) + 64);                                                        \
    GLDSB((KT) + 64, (CB) ^ 1);                                              \
    asm volatile("s_waitcnt vmcnt(6) lgkmcnt(0)" ::: "memory"); /* B[k] */   \
    block_sync();                                                            \
    MFMAK(CB);                                                               \
    block_sync();                                                            \
  } while (0)

  LOADA(0);
  GLDSB(0, 0);
  for (int kt = 0; kt < 896; kt += 128) {   // tiles 0..13
    STEPF(kt, 0);
    STEPF(kt + 64, 1);
  }
  STEPF(896, 0);   // tile 14 (issues tile 15 -> buf 1)
  {                // tile 15: drain
    asm volatile("s_waitcnt vmcnt(2)" ::: "memory");
    WRITEA();
    asm volatile("s_waitcnt vmcnt(0) lgkmcnt(0)" ::: "memory");
    block_sync();
    MFMAK(1);
    block_sync();
  }
#undef STEPF

  // epilogues: one head per block (head = bx); LDS transpose -> u16x8 stores
  const size_t bh = (size_t)(arow0 >> 11) * 16 + bx;
  const int sbase = arow0 & 2047;
  u16* T = lds;  // 8KB scratch [64][64], swizzled rows
  if (z == 2) {
    // V: T[d][s] -> Vt[bh*64+d][sbase+s]
#pragma unroll
    for (int m = 0; m < 2; m++)
#pragma unroll
      for (int n = 0; n < 2; n++)
#pragma unroll
        for (int r = 0; r < 4; r++) {
          int sl = wr + m * 16 + lg * 4 + r;
          int cl = wc + n * 16 + lr;
          T[cl * 64 + (sl ^ ((cl & 7) << 3))] = f2bf(acc[m][n][r]);
        }
    __syncthreads();
    const int d = tid >> 2, s0 = (tid & 3) * 16;
    const int swz = (d & 7) << 3;
    u16* vd = Vt + (bh * 64 + d) * 2048 + sbase;
    *(u16x8*)&vd[s0] = *(const u16x8*)&T[d * 64 + (s0 ^ swz)];
    *(u16x8*)&vd[s0 + 8] = *(const u16x8*)&T[d * 64 + ((s0 + 8) ^ swz)];
  } else {
    // Q/K: T[s][d] -> dst[(bh*2048+sbase+s)*64 + d]
    const float scale = (z == 0) ? 0.18033688f : 1.0f;  // 0.125 * log2(e)
    u16* dst = (z == 0) ? Qh : Kh;
#pragma unroll
    for (int m = 0; m < 2; m++)
#pragma unroll
      for (int n = 0; n < 2; n++)
#pragma unroll
        for (int r = 0; r < 4; r++) {
          int sl = wr + m * 16 + lg * 4 + r;
          int cl = wc + n * 16 + lr;
          T[sl * 64 + (cl ^ ((sl & 7) << 3))] = f2bf(acc[m][n][r] * scale);
        }
    __syncthreads();
    const int s = tid >> 2, c0 = (tid & 3) * 16;
    const int swz = (s & 7) << 3;
    u16* qd = dst + (bh * 2048 + (size_t)(sbase + s)) * 64;
    *(u16x8*)&qd[c0] = *(const u16x8*)&T[s * 64 + (c0 ^ swz)];
    *(u16x8*)&qd[c0 + 8] = *(const u16x8*)&T[s * 64 + ((c0 + 8) ^ swz)];
  }
}

// ---------- kernel 3: flash attention (swapped QK^T, P in registers) ----------
// 512 blocks (XCD-swizzled) x 8 waves, 128 q-rows per block, 16 per wave.
// Quad-buffered K/V (64KB LDS), 2-deep prefetch, steady vmcnt(6);
// launch_bounds(512,4) -> 2 blocks/CU = 16 waves/CU, grid exactly resident.
__global__ __launch_bounds__(512, 4) void attn_kernel(
    const u16* __restrict__ Qh, const u16* __restrict__ Kh,
    const u16* __restrict__ Vt, u16* __restrict__ Ob) {
  __shared__ u16 kt[4][64 * 64];  // K tiles [key][d], h-swizzled rows
  __shared__ u16 vt[4][64 * 64];  // V^T tiles [d][s], xor-swizzled rows
  const int tid = threadIdx.x;
  const int lane = tid & 63, wave = tid >> 6;
  const int lr = lane & 15, lg = lane >> 4;
  const int id = blockIdx.x;
  const int swz = (id & 7) * 64 + (id >> 3);
  const int bh = swz >> 4;
  const int q0 = (swz & 15) * 128;
  const u16* Qb = Qh + ((size_t)bh * 2048 + q0) * 64;
  const u16* Kb = Kh + (size_t)bh * 2048 * 64;
  const u16* Vb = Vt + (size_t)bh * 64 * 2048;

  bf16x8 aq[2];
#pragma unroll
  for (int kk = 0; kk < 2; kk++)
    aq[kk] = *(const bf16x8*)(Qb + (wave * 16 + lr) * 64 + kk * 32 + lg * 8);

  const int hsw = (lr & 3) | (((lr >> 2) & 1) << 2);
  int koff[2][4];
#pragma unroll
  for (int n = 0; n < 4; n++) {
    int kr = 32 * (n >> 1) + 8 * (lr >> 2) + 4 * (n & 1) + (lr & 3);
#pragma unroll
    for (int kk = 0; kk < 2; kk++)
      koff[kk][n] = kr * 64 + ((kk * 32 + lg * 8) ^ (hsw << 3));
  }
  int voff[2][4];
#pragma unroll
  for (int n = 0; n < 4; n++) {
    int d = n * 16 + lr;
#pragma unroll
    for (int ks = 0; ks < 2; ks++)
      voff[ks][n] = d * 64 + ((ks * 32 + lg * 8) ^ ((d & 7) << 3));
  }

  const int o0 = tid * 8;
  const int srow = tid >> 3, sch = tid & 7;
  const int hk = (srow & 3) | (((srow >> 3) & 1) << 2);
  const u16* kg = Kb + (size_t)srow * 64 + ((sch ^ hk) << 3);
  const u16* vg = Vb + (size_t)srow * 2048 + ((sch ^ (srow & 7)) << 3);

  f32x4 oacc[4] = {};
  float mrun = -1e30f, lrun = 0.f;

  auto STAGE = [&](int t, int b) {
    GLDS16(kg + (size_t)t * 4096, &kt[0][0] + b * 4096 + o0);
    GLDS16(vg + t * 64, &vt[0][0] + b * 4096 + o0);
  };

  auto COMPUTE = [&](int cur) {
    f32x4 sacc[4] = {};
    __builtin_amdgcn_s_setprio(1);
#pragma unroll
    for (int kk = 0; kk < 2; kk++) {
#pragma unroll
      for (int n = 0; n < 4; n++) {
        bf16x8 ka = *(const bf16x8*)&kt[cur][koff[kk][n]];
        sacc[n] = __builtin_amdgcn_mfma_f32_16x16x32_bf16(ka, aq[kk],
                                                          sacc[n], 0, 0, 0);
      }
    }
    __builtin_amdgcn_s_setprio(0);
    float t0 = fmax3(sacc[0][0], sacc[0][1], sacc[0][2]);
    float t1 = fmax3(sacc[0][3], sacc[1][0], sacc[1][1]);
    float t2 = fmax3(sacc[1][2], sacc[1][3], sacc[2][0]);
    float t3 = fmax3(sacc[2][1], sacc[2][2], sacc[2][3]);
    float t4 = fmax3(sacc[3][0], sacc[3][1], sacc[3][2]);
    float mx = fmaxf(fmax3(t0, t1, t2), fmax3(t3, t4, sacc[3][3]));
    mx = fmaxf(mx, __shfl_xor(mx, 16));
    mx = fmaxf(mx, __shfl_xor(mx, 32));
    float mnew = fmaxf(mrun, mx);
    if (__all(mx - mrun <= 8.0f)) {
      mnew = mrun;
    } else {
      float corr = EXP2(mrun - mnew);
      mrun = mnew;
      lrun *= corr;
      float cr[4];
#pragma unroll
      for (int r = 0; r < 4; r++) cr[r] = __shfl(corr, lg * 4 + r);
#pragma unroll
      for (int n = 0; n < 4; n++)
#pragma unroll
        for (int r = 0; r < 4; r++) oacc[n][r] *= cr[r];
    }
    float psum = 0.f;
#pragma unroll
    for (int n = 0; n < 4; n++)
#pragma unroll
      for (int r = 0; r < 4; r++) {
        float p = EXP2(sacc[n][r] - mnew);
        sacc[n][r] = p;
        psum += p;
      }
    psum += __shfl_xor(psum, 16);
    psum += __shfl_xor(psum, 32);
    lrun += psum;
    u32x4 w0 = {cvt_pk_bf16(sacc[0][0], sacc[0][1]),
                cvt_pk_bf16(sacc[0][2], sacc[0][3]),
                cvt_pk_bf16(sacc[1][0], sacc[1][1]),
                cvt_pk_bf16(sacc[1][2], sacc[1][3])};
    u32x4 w1 = {cvt_pk_bf16(sacc[2][0], sacc[2][1]),
                cvt_pk_bf16(sacc[2][2], sacc[2][3]),
                cvt_pk_bf16(sacc[3][0], sacc[3][1]),
                cvt_pk_bf16(sacc[3][2], sacc[3][3])};
    bf16x8 pa0 = __builtin_bit_cast(bf16x8, w0);
    bf16x8 pa1 = __builtin_bit_cast(bf16x8, w1);
    __builtin_amdgcn_s_setprio(1);
#pragma unroll
    for (int ks = 0; ks < 2; ks++) {
      bf16x8 ap = ks ? pa1 : pa0;
      bf16x8 bv[4];
#pragma unroll
      for (int n = 0; n < 4; n++)
        bv[n] = *(const bf16x8*)&vt[cur][voff[ks][n]];
#pragma unroll
      for (int n = 0; n < 4; n++)
        oacc[n] = __builtin_amdgcn_mfma_f32_16x16x32_bf16(ap, bv[n],
                                                          oacc[n], 0, 0, 0);
    }
    __builtin_amdgcn_s_setprio(0);
  };

#define VMC6 asm volatile("s_waitcnt vmcnt(6)" ::: "memory")
#define VMC4 asm volatile("s_waitcnt vmcnt(4)" ::: "memory")
#define VMC2 asm volatile("s_waitcnt vmcnt(2)" ::: "memory")
#define VMC0 asm volatile("s_waitcnt vmcnt(0)" ::: "memory")
  STAGE(0, 0); STAGE(1, 1); STAGE(2, 2);
  for (int t = 0; t < 28; t += 4) {
    STAGE(t + 3, 3); VMC6; block_sync(); COMPUTE(0); block_sync();
    STAGE(t + 4, 0); VMC6; block_sync(); COMPUTE(1); block_sync();
    STAGE(t + 5, 1); VMC6; block_sync(); COMPUTE(2); block_sync();
    STAGE(t + 6, 2); VMC6; block_sync(); COMPUTE(3); block_sync();
  }
  STAGE(31, 3); VMC6; block_sync(); COMPUTE(0); block_sync();  // tile 28
  VMC4; block_sync(); COMPUTE(1); block_sync();                // tile 29
  VMC2; block_sync(); COMPUTE(2); block_sync();                // tile 30
  VMC0; block_sync(); COMPUTE(3);                              // tile 31
#undef VMC6
#undef VMC4
#undef VMC2
#undef VMC0

  const int b = bh >> 4, h = bh & 15;
  float inv = 1.0f / lrun;
  float ivr[4];
#pragma unroll
  for (int r = 0; r < 4; r++) ivr[r] = __shfl(inv, lg * 4 + r);
#pragma unroll
  for (int r = 0; r < 4; r++) {
    int qrow = q0 + wave * 16 + lg * 4 + r;
#pragma unroll
    for (int n = 0; n < 4; n++) {
      int d = n * 16 + lr;
      Ob[((size_t)b * 2048 + qrow) * 1024 + h * 64 + d] = f2bf(oacc[n][r] * ivr[r]);
    }
  }
}

// ---------- kernel 4: output projection (128x64 tile, XCD-chunked 512 blocks) ----------
__global__ __launch_bounds__(256) void outproj_kernel(
    const u16* __restrict__ Ob, const u16* __restrict__ WoT,
    float* __restrict__ out) {
  __shared__ u16 ldsA[128 * 64];  // 16KB, swizzled rows
  __shared__ u16 ldsB[64 * 64];   //  8KB, swizzled rows
  const int tid = threadIdx.x;
  const int lane = tid & 63, wave = tid >> 6;
  const int lr = lane & 15, lg = lane >> 4;
  const int wr = (wave >> 1) * 64;  // M offset (0/64)
  const int wc = (wave & 1) * 32;   // N offset (0/32)
  const int id = blockIdx.x;
  const int xcd = id & 7, l = id >> 3;   // l in [0,64)
  const int by = xcd * 4 + (l >> 4);     // 0..31
  const int bx = l & 15;                 // 0..15
  const int arow0 = by * 128, bcol0 = bx * 64;
  f32x4 acc[4][2] = {};
  for (int kt = 0; kt < 1024; kt += 64) {
#pragma unroll
    for (int i = 0; i < 4; i++) {
      int o = (i * 256 + tid) * 8;
      int row = o >> 6, ch = (o >> 3) & 7;
      int sc = (ch ^ (row & 7)) << 3;
      GLDS16(Ob + (size_t)(arow0 + row) * 1024 + kt + sc, &ldsA[o]);
    }
#pragma unroll
    for (int i = 0; i < 2; i++) {
      int o = (i * 256 + tid) * 8;
      int row = o >> 6, ch = (o >> 3) & 7;
      int sc = (ch ^ (row & 7)) << 3;
      GLDS16(WoT + (size_t)(bcol0 + row) * 1024 + kt + sc, &ldsB[o]);
    }
    __syncthreads();
#pragma unroll
    for (int kk = 0; kk < 2; kk++) {
      const int ke = kk * 32 + lg * 8;
      bf16x8 af[4], bfr[2];
#pragma unroll
      for (int m = 0; m < 4; m++) {
        int row = wr + m * 16 + lr;
        af[m] = *(const bf16x8*)&ldsA[row * 64 + (ke ^ ((row & 7) << 3))];
      }
#pragma unroll
      for (int n = 0; n < 2; n++) {
        int row = wc + n * 16 + lr;
        bfr[n] = *(const bf16x8*)&ldsB[row * 64 + (ke ^ ((row & 7) << 3))];
      }
#pragma unroll
      for (int m = 0; m < 4; m++)
#pragma unroll
        for (int n = 0; n < 2; n++)
          acc[m][n] = __builtin_amdgcn_mfma_f32_16x16x32_bf16(af[m], bfr[n],
                                                              acc[m][n], 0, 0, 0);
    }
    __syncthreads();
  }
#pragma unroll
  for (int m = 0; m < 4; m++)
#pragma unroll
    for (int n = 0; n < 2; n++)
#pragma unroll
      for (int r = 0; r < 4; r++) {
        int gr = arow0 + wr + m * 16 + lg * 4 + r;
        int gc = bcol0 + wc + n * 16 + lr;
        out[(size_t)gr * 1024 + gc] = acc[m][n][r];
      }
}

extern "C" void kernel_launch(void* const* d_in, const int* in_sizes, int n_in,
                              void* d_out, int out_size, void* d_ws, size_t ws_size,
                              hipStream_t stream) {
  const float* q  = (const float*)d_in[0];
  const float* k  = (const float*)d_in[1];
  const float* v  = (const float*)d_in[2];
  const float* wq = (const float*)d_in[3];
  const float* wk = (const float*)d_in[4];
  const float* wv = (const float*)d_in[5];
  const float* wo = (const float*)d_in[6];
  float* out = (float*)d_out;
  char* ws = (char*)d_ws;

  u16* WT = (u16*)ws;                                    // [4][1024][1024]
  u16* Qh = (u16*)(ws + (size_t)32 * 1024 * 1024);       // [32][2048][64]
  u16* Kh = (u16*)(ws + (size_t)40 * 1024 * 1024);       // [32][2048][64]
  u16* Vt = (u16*)(ws + (size_t)48 * 1024 * 1024);       // [32][64][2048]
  u16* Ob = (u16*)(ws + (size_t)56 * 1024 * 1024);       // [4096][1024]

  wtrans_kernel<<<dim3(32, 32, 4), 256, 0, stream>>>(wq, wk, wv, wo, WT);
  proj_kernel<<<dim3(3072), 256, 0, stream>>>(q, k, v, WT, Qh, Kh, Vt);
  attn_kernel<<<dim3(512), 512, 0, stream>>>(Qh, Kh, Vt, Ob);
  outproj_kernel<<<dim3(512), 256, 0, stream>>>(Ob, WT + (size_t)3 * 1024 * 1024, out);
}

// Round 16
// 121.999 us; speedup vs baseline: 1.3222x; 1.0952x over previous
//
#include <hip/hip_runtime.h>
#include <hip/hip_bf16.h>

// B=2, S=2048, H=16, D=64, D_MODEL=1024, M=B*S=4096
// ws layout (bytes):
//   WT  @ 0MB  : [4][1024][1024] bf16 (w_q^T, w_k^T, w_v^T, w_o^T)  8MB
//   Qh  @ 32MB : [32][2048][64]  bf16 (scaled by 0.125*log2e)       8MB
//   Kh  @ 40MB : [32][2048][64]  bf16                               8MB
//   Vt  @ 48MB : [32][64][2048]  bf16 (per-head transposed V)       8MB
//   Ob  @ 56MB : [4096][1024]    bf16 (attention output)            8MB

using bf16x8 = __attribute__((ext_vector_type(8))) short;
using f32x4  = __attribute__((ext_vector_type(4))) float;
using u32x4  = __attribute__((ext_vector_type(4))) unsigned;
using u32x2  = __attribute__((ext_vector_type(2))) unsigned;
typedef unsigned short u16;
using u16x8 = __attribute__((ext_vector_type(8))) u16;

#define GLDS16(g, l) __builtin_amdgcn_global_load_lds( \
    (const __attribute__((address_space(1))) void*)(g), \
    (__attribute__((address_space(3))) void*)(l), 16, 0, 0)

#if __has_builtin(__builtin_amdgcn_exp2f)
#define EXP2(x) __builtin_amdgcn_exp2f(x)
#else
#define EXP2(x) exp2f(x)
#endif

// Raw s_barrier is IntrNoMem: pair it with compiler memory fences so LDS
// reads/writes cannot be moved across it at compile time.
__device__ __forceinline__ void block_sync() {
  __builtin_amdgcn_sched_barrier(0);
  asm volatile("" ::: "memory");
  __builtin_amdgcn_s_barrier();
  asm volatile("" ::: "memory");
  __builtin_amdgcn_sched_barrier(0);
}

__device__ __forceinline__ u16 f2bf(float f) {
  unsigned u = __builtin_bit_cast(unsigned, f);
  u += 0x7fffu + ((u >> 16) & 1u);
  return (u16)(u >> 16);
}

// packed f32->bf16 RNE (no builtin on gfx950; T12 primitive)
__device__ __forceinline__ unsigned cvt_pk_bf16(float lo, float hi) {
  unsigned r;
  asm("v_cvt_pk_bf16_f32 %0, %1, %2" : "=v"(r) : "v"(lo), "v"(hi));
  return r;
}

__device__ __forceinline__ float fmax3(float a, float b, float c) {
  return fmaxf(fmaxf(a, b), c);  // clang fuses to v_max3_f32
}

// ---------- kernel 1: weight transpose+convert: WT[z][n][k] = bf16(w_z[k][n]) ----------
__global__ __launch_bounds__(256) void wtrans_kernel(
    const float* __restrict__ wq, const float* __restrict__ wk,
    const float* __restrict__ wv, const float* __restrict__ wo,
    u16* __restrict__ dst) {
  __shared__ float t[32][33];
  const int z = blockIdx.z;
  const float* src = (z == 0) ? wq : (z == 1) ? wk : (z == 2) ? wv : wo;
  u16* d = dst + (size_t)z * 1024 * 1024;
  const int tx = threadIdx.x & 31, ty = threadIdx.x >> 5;
  const int bx = blockIdx.x * 32, by = blockIdx.y * 32;
#pragma unroll
  for (int j = 0; j < 4; j++)
    t[ty + j * 8][tx] = src[(size_t)(by + ty + j * 8) * 1024 + bx + tx];
  __syncthreads();
#pragma unroll
  for (int j = 0; j < 4; j++)
    d[(size_t)(bx + ty + j * 8) * 1024 + by + tx] = f2bf(t[tx][ty + j * 8]);
}

// ---------- kernel 2: fused QKV projections (128x128 tile + R15 pipeline) ----------
// Recombination of validated parts:
//  - R12's 128x128 tile (best proj time, 4x MFMA density of R15's 64x64)
//  - R15's STEPF ordering: vmcnt(4) drain A[k] -> WRITEA (consume fa BEFORE
//    reload) -> LOADA/GLDSB k+1 -> vmcnt(12) drain B[k]; 12 loads in flight
//  - R13's validated LDS-transpose epilogues (kills write-amp + RMW fetch)
// 768 blocks; xcd=id&7 owns 4 y-panels x 8 bx per z -> A read by ONE XCD.
// VGPR: acc 64 + fa 32 + addr ~30 < 170 cap (256,3). LDS 48KB -> 3 blocks/CU.
__global__ __launch_bounds__(256, 3) void proj_kernel(
    const float* __restrict__ qf, const float* __restrict__ kf,
    const float* __restrict__ vf, const u16* __restrict__ WT,
    u16* __restrict__ Qh, u16* __restrict__ Kh, u16* __restrict__ Vt) {
  __shared__ u16 lds[24576];   // [0,8192): A; [8192,16384): B0; [16384,24576): B1
  const int id = blockIdx.x;
  const int xcd = id & 7, l = id >> 3;      // l in [0,96)
  const int z = l >> 5, rem = l & 31;       // 32 blocks per XCD per z
  const int by = xcd * 4 + (rem >> 3);      // 4 y-panels per XCD
  const int bx = rem & 7;
  const int arow0 = by * 128, bcol0 = bx * 128;
  const float* A = (z == 0) ? qf : (z == 1) ? kf : vf;
  const u16* Bw = WT + (size_t)z * 1024 * 1024;

  const int tid = threadIdx.x;
  const int lane = tid & 63, wave = tid >> 6;
  const int lr = lane & 15, lg = lane >> 4;
  const int wr = (wave >> 1) * 64, wc = (wave & 1) * 64;
  const int ar = tid >> 3, ac = tid & 7;    // A stage: row base (0..31), chunk
  f32x4 acc[4][4] = {};
  f32x4 fa[4][2];    // 32 VGPRs in-flight A (tile k)

  auto LOADA = [&](int kt) {
#pragma unroll
    for (int i = 0; i < 4; i++) {
      const float* ap = A + (size_t)(arow0 + i * 32 + ar) * 1024 + kt + ac * 8;
      fa[i][0] = *(const f32x4*)ap;
      fa[i][1] = *(const f32x4*)(ap + 4);
    }
  };
  auto GLDSB = [&](int kt, int nb) {
    u16* bd = lds + 8192 + nb * 8192;
#pragma unroll
    for (int i = 0; i < 4; i++) {
      int o = (i * 256 + tid) * 8;
      int row = o >> 6, ch = (o >> 3) & 7;
      GLDS16(Bw + (size_t)(bcol0 + row) * 1024 + kt + ((ch ^ (row & 7)) << 3),
             bd + o);
    }
  };
  auto WRITEA = [&]() {  // cvt fa -> bf16, swizzled ds_write (16B per i)
#pragma unroll
    for (int i = 0; i < 4; i++) {
      int row = i * 32 + ar;
      u32x4 v = {cvt_pk_bf16(fa[i][0][0], fa[i][0][1]),
                 cvt_pk_bf16(fa[i][0][2], fa[i][0][3]),
                 cvt_pk_bf16(fa[i][1][0], fa[i][1][1]),
                 cvt_pk_bf16(fa[i][1][2], fa[i][1][3])};
      *(u32x4*)&lds[row * 64 + ((ac ^ (row & 7)) << 3)] = v;
    }
  };
  auto MFMAK = [&](int cb) {
    const u16* Bb = lds + 8192 + cb * 8192;
#pragma unroll
    for (int kk = 0; kk < 2; kk++) {
      bf16x8 af[4], bfr[4];
      const int ke = kk * 32 + lg * 8;
#pragma unroll
      for (int m = 0; m < 4; m++) {
        int row = wr + m * 16 + lr;
        af[m] = *(const bf16x8*)&lds[row * 64 + (ke ^ ((row & 7) << 3))];
      }
#pragma unroll
      for (int n = 0; n < 4; n++) {
        int row = wc + n * 16 + lr;
        bfr[n] = *(const bf16x8*)&Bb[row * 64 + (ke ^ ((row & 7) << 3))];
      }
#pragma unroll
      for (int m = 0; m < 4; m++)
#pragma unroll
        for (int n = 0; n < 4; n++)
          acc[m][n] = __builtin_amdgcn_mfma_f32_16x16x32_bf16(af[m], bfr[n],
                                                              acc[m][n], 0, 0, 0);
    }
  };

  // vmcnt queue at step entry: [A[k](8), B[k](4)]
#define STEPF(KT, CB)                                                        \
  do {                                                                       \
    asm volatile("s_waitcnt vmcnt(4)" ::: "memory");  /* A[k] landed */      \
    WRITEA();                          /* consume fa BEFORE reload */        \
    LOADA((KT) + 64);                                                        \
    GLDSB((KT) + 64, (CB) ^ 1);                                              \
    asm volatile("s_waitcnt vmcnt(12) lgkmcnt(0)" ::: "memory"); /* B[k] */  \
    block_sync();                                                            \
    MFMAK(CB);                                                               \
    block_sync();                                                            \
  } while (0)

  LOADA(0);
  GLDSB(0, 0);
  for (int kt = 0; kt < 896; kt += 128) {   // tiles 0..13
    STEPF(kt, 0);
    STEPF(kt + 64, 1);
  }
  STEPF(896, 0);   // tile 14 (issues tile 15 -> buf 1)
  {                // tile 15: drain
    asm volatile("s_waitcnt vmcnt(4)" ::: "memory");
    WRITEA();
    asm volatile("s_waitcnt vmcnt(0) lgkmcnt(0)" ::: "memory");
    block_sync();
    MFMAK(1);
    block_sync();
  }
#undef STEPF

  // epilogues (R13-validated): LDS transpose -> u16x8 stores
  if (z == 2) {
    // V: T[c][s] (128x128, swizzled) -> Vt[(b*16+h)*64+d][s]
    u16* T = lds;
#pragma unroll
    for (int m = 0; m < 4; m++)
#pragma unroll
      for (int n = 0; n < 4; n++)
#pragma unroll
        for (int r = 0; r < 4; r++) {
          int sl = wr + m * 16 + lg * 4 + r;
          int cl = wc + n * 16 + lr;
          T[cl * 128 + (sl ^ ((cl & 7) << 3))] = f2bf(acc[m][n][r]);
        }
    __syncthreads();
    const int t = threadIdx.x;
    const int cl = t >> 1, s0 = (t & 1) * 64;
    const int gc = bcol0 + cl;
    const size_t vrow = ((size_t)(arow0 >> 11) * 16 + (gc >> 6)) * 64 + (gc & 63);
#pragma unroll
    for (int j = 0; j < 8; j++) {
      int sl = s0 + j * 8;
      u16x8 vv = *(const u16x8*)&T[cl * 128 + (sl ^ ((cl & 7) << 3))];
      *(u16x8*)&Vt[vrow * 2048 + (size_t)((arow0 & 2047) + sl)] = vv;
    }
  } else {
    // Q/K: T[s][c] (128x128, swizzled) -> dst[(bh*2048+s)*64 + c]
    const float scale = (z == 0) ? 0.18033688f : 1.0f;  // 0.125 * log2(e)
    u16* dst = (z == 0) ? Qh : Kh;
    u16* T = lds;
#pragma unroll
    for (int m = 0; m < 4; m++)
#pragma unroll
      for (int n = 0; n < 4; n++)
#pragma unroll
        for (int r = 0; r < 4; r++) {
          int sl = wr + m * 16 + lg * 4 + r;
          int cl = wc + n * 16 + lr;
          T[sl * 128 + (cl ^ ((sl & 7) << 3))] = f2bf(acc[m][n][r] * scale);
        }
    __syncthreads();
    const int t = threadIdx.x;
    const int h2 = t >> 7, tt = t & 127;
    const int rb = tt >> 3, c0 = (tt & 7) * 8;
    const size_t bh = (size_t)(arow0 >> 11) * 16 + bx * 2 + h2;
#pragma unroll
    for (int j = 0; j < 8; j++) {
      int row = j * 16 + rb;
      int cl = h2 * 64 + c0;
      u16x8 vv = *(const u16x8*)&T[row * 128 + (cl ^ ((row & 7) << 3))];
      *(u16x8*)&dst[(bh * 2048 + (size_t)((arow0 & 2047) + row)) * 64 + c0] = vv;
    }
  }
}

// ---------- kernel 3: flash attention (swapped QK^T, P in registers) ----------
// 512 blocks (XCD-swizzled) x 8 waves, 128 q-rows per block, 16 per wave.
// Quad-buffered K/V (64KB LDS), 2-deep prefetch, steady vmcnt(6);
// launch_bounds(512,4) -> 2 blocks/CU = 16 waves/CU, grid exactly resident.
__global__ __launch_bounds__(512, 4) void attn_kernel(
    const u16* __restrict__ Qh, const u16* __restrict__ Kh,
    const u16* __restrict__ Vt, u16* __restrict__ Ob) {
  __shared__ u16 kt[4][64 * 64];  // K tiles [key][d], h-swizzled rows
  __shared__ u16 vt[4][64 * 64];  // V^T tiles [d][s], xor-swizzled rows
  const int tid = threadIdx.x;
  const int lane = tid & 63, wave = tid >> 6;
  const int lr = lane & 15, lg = lane >> 4;
  const int id = blockIdx.x;
  const int swz = (id & 7) * 64 + (id >> 3);
  const int bh = swz >> 4;
  const int q0 = (swz & 15) * 128;
  const u16* Qb = Qh + ((size_t)bh * 2048 + q0) * 64;
  const u16* Kb = Kh + (size_t)bh * 2048 * 64;
  const u16* Vb = Vt + (size_t)bh * 64 * 2048;

  bf16x8 aq[2];
#pragma unroll
  for (int kk = 0; kk < 2; kk++)
    aq[kk] = *(const bf16x8*)(Qb + (wave * 16 + lr) * 64 + kk * 32 + lg * 8);

  const int hsw = (lr & 3) | (((lr >> 2) & 1) << 2);
  int koff[2][4];
#pragma unroll
  for (int n = 0; n < 4; n++) {
    int kr = 32 * (n >> 1) + 8 * (lr >> 2) + 4 * (n & 1) + (lr & 3);
#pragma unroll
    for (int kk = 0; kk < 2; kk++)
      koff[kk][n] = kr * 64 + ((kk * 32 + lg * 8) ^ (hsw << 3));
  }
  int voff[2][4];
#pragma unroll
  for (int n = 0; n < 4; n++) {
    int d = n * 16 + lr;
#pragma unroll
    for (int ks = 0; ks < 2; ks++)
      voff[ks][n] = d * 64 + ((ks * 32 + lg * 8) ^ ((d & 7) << 3));
  }

  const int o0 = tid * 8;
  const int srow = tid >> 3, sch = tid & 7;
  const int hk = (srow & 3) | (((srow >> 3) & 1) << 2);
  const u16* kg = Kb + (size_t)srow * 64 + ((sch ^ hk) << 3);
  const u16* vg = Vb + (size_t)srow * 2048 + ((sch ^ (srow & 7)) << 3);

  f32x4 oacc[4] = {};
  float mrun = -1e30f, lrun = 0.f;

  auto STAGE = [&](int t, int b) {
    GLDS16(kg + (size_t)t * 4096, &kt[0][0] + b * 4096 + o0);
    GLDS16(vg + t * 64, &vt[0][0] + b * 4096 + o0);
  };

  auto COMPUTE = [&](int cur) {
    f32x4 sacc[4] = {};
    __builtin_amdgcn_s_setprio(1);
#pragma unroll
    for (int kk = 0; kk < 2; kk++) {
#pragma unroll
      for (int n = 0; n < 4; n++) {
        bf16x8 ka = *(const bf16x8*)&kt[cur][koff[kk][n]];
        sacc[n] = __builtin_amdgcn_mfma_f32_16x16x32_bf16(ka, aq[kk],
                                                          sacc[n], 0, 0, 0);
      }
    }
    __builtin_amdgcn_s_setprio(0);
    float t0 = fmax3(sacc[0][0], sacc[0][1], sacc[0][2]);
    float t1 = fmax3(sacc[0][3], sacc[1][0], sacc[1][1]);
    float t2 = fmax3(sacc[1][2], sacc[1][3], sacc[2][0]);
    float t3 = fmax3(sacc[2][1], sacc[2][2], sacc[2][3]);
    float t4 = fmax3(sacc[3][0], sacc[3][1], sacc[3][2]);
    float mx = fmaxf(fmax3(t0, t1, t2), fmax3(t3, t4, sacc[3][3]));
    mx = fmaxf(mx, __shfl_xor(mx, 16));
    mx = fmaxf(mx, __shfl_xor(mx, 32));
    float mnew = fmaxf(mrun, mx);
    if (__all(mx - mrun <= 8.0f)) {
      mnew = mrun;
    } else {
      float corr = EXP2(mrun - mnew);
      mrun = mnew;
      lrun *= corr;
      float cr[4];
#pragma unroll
      for (int r = 0; r < 4; r++) cr[r] = __shfl(corr, lg * 4 + r);
#pragma unroll
      for (int n = 0; n < 4; n++)
#pragma unroll
        for (int r = 0; r < 4; r++) oacc[n][r] *= cr[r];
    }
    float psum = 0.f;
#pragma unroll
    for (int n = 0; n < 4; n++)
#pragma unroll
      for (int r = 0; r < 4; r++) {
        float p = EXP2(sacc[n][r] - mnew);
        sacc[n][r] = p;
        psum += p;
      }
    psum += __shfl_xor(psum, 16);
    psum += __shfl_xor(psum, 32);
    lrun += psum;
    u32x4 w0 = {cvt_pk_bf16(sacc[0][0], sacc[0][1]),
                cvt_pk_bf16(sacc[0][2], sacc[0][3]),
                cvt_pk_bf16(sacc[1][0], sacc[1][1]),
                cvt_pk_bf16(sacc[1][2], sacc[1][3])};
    u32x4 w1 = {cvt_pk_bf16(sacc[2][0], sacc[2][1]),
                cvt_pk_bf16(sacc[2][2], sacc[2][3]),
                cvt_pk_bf16(sacc[3][0], sacc[3][1]),
                cvt_pk_bf16(sacc[3][2], sacc[3][3])};
    bf16x8 pa0 = __builtin_bit_cast(bf16x8, w0);
    bf16x8 pa1 = __builtin_bit_cast(bf16x8, w1);
    __builtin_amdgcn_s_setprio(1);
#pragma unroll
    for (int ks = 0; ks < 2; ks++) {
      bf16x8 ap = ks ? pa1 : pa0;
      bf16x8 bv[4];
#pragma unroll
      for (int n = 0; n < 4; n++)
        bv[n] = *(const bf16x8*)&vt[cur][voff[ks][n]];
#pragma unroll
      for (int n = 0; n < 4; n++)
        oacc[n] = __builtin_amdgcn_mfma_f32_16x16x32_bf16(ap, bv[n],
                                                          oacc[n], 0, 0, 0);
    }
    __builtin_amdgcn_s_setprio(0);
  };

#define VMC6 asm volatile("s_waitcnt vmcnt(6)" ::: "memory")
#define VMC4 asm volatile("s_waitcnt vmcnt(4)" ::: "memory")
#define VMC2 asm volatile("s_waitcnt vmcnt(2)" ::: "memory")
#define VMC0 asm volatile("s_waitcnt vmcnt(0)" ::: "memory")
  STAGE(0, 0); STAGE(1, 1); STAGE(2, 2);
  for (int t = 0; t < 28; t += 4) {
    STAGE(t + 3, 3); VMC6; block_sync(); COMPUTE(0); block_sync();
    STAGE(t + 4, 0); VMC6; block_sync(); COMPUTE(1); block_sync();
    STAGE(t + 5, 1); VMC6; block_sync(); COMPUTE(2); block_sync();
    STAGE(t + 6, 2); VMC6; block_sync(); COMPUTE(3); block_sync();
  }
  STAGE(31, 3); VMC6; block_sync(); COMPUTE(0); block_sync();  // tile 28
  VMC4; block_sync(); COMPUTE(1); block_sync();                // tile 29
  VMC2; block_sync(); COMPUTE(2); block_sync();                // tile 30
  VMC0; block_sync(); COMPUTE(3);                              // tile 31
#undef VMC6
#undef VMC4
#undef VMC2
#undef VMC0

  const int b = bh >> 4, h = bh & 15;
  float inv = 1.0f / lrun;
  float ivr[4];
#pragma unroll
  for (int r = 0; r < 4; r++) ivr[r] = __shfl(inv, lg * 4 + r);
#pragma unroll
  for (int r = 0; r < 4; r++) {
    int qrow = q0 + wave * 16 + lg * 4 + r;
#pragma unroll
    for (int n = 0; n < 4; n++) {
      int d = n * 16 + lr;
      Ob[((size_t)b * 2048 + qrow) * 1024 + h * 64 + d] = f2bf(oacc[n][r] * ivr[r]);
    }
  }
}

// ---------- kernel 4: output projection (128x64 tile, XCD-chunked 512 blocks) ----------
__global__ __launch_bounds__(256) void outproj_kernel(
    const u16* __restrict__ Ob, const u16* __restrict__ WoT,
    float* __restrict__ out) {
  __shared__ u16 ldsA[128 * 64];  // 16KB, swizzled rows
  __shared__ u16 ldsB[64 * 64];   //  8KB, swizzled rows
  const int tid = threadIdx.x;
  const int lane = tid & 63, wave = tid >> 6;
  const int lr = lane & 15, lg = lane >> 4;
  const int wr = (wave >> 1) * 64;  // M offset (0/64)
  const int wc = (wave & 1) * 32;   // N offset (0/32)
  const int id = blockIdx.x;
  const int xcd = id & 7, l = id >> 3;   // l in [0,64)
  const int by = xcd * 4 + (l >> 4);     // 0..31
  const int bx = l & 15;                 // 0..15
  const int arow0 = by * 128, bcol0 = bx * 64;
  f32x4 acc[4][2] = {};
  for (int kt = 0; kt < 1024; kt += 64) {
#pragma unroll
    for (int i = 0; i < 4; i++) {
      int o = (i * 256 + tid) * 8;
      int row = o >> 6, ch = (o >> 3) & 7;
      int sc = (ch ^ (row & 7)) << 3;
      GLDS16(Ob + (size_t)(arow0 + row) * 1024 + kt + sc, &ldsA[o]);
    }
#pragma unroll
    for (int i = 0; i < 2; i++) {
      int o = (i * 256 + tid) * 8;
      int row = o >> 6, ch = (o >> 3) & 7;
      int sc = (ch ^ (row & 7)) << 3;
      GLDS16(WoT + (size_t)(bcol0 + row) * 1024 + kt + sc, &ldsB[o]);
    }
    __syncthreads();
#pragma unroll
    for (int kk = 0; kk < 2; kk++) {
      const int ke = kk * 32 + lg * 8;
      bf16x8 af[4], bfr[2];
#pragma unroll
      for (int m = 0; m < 4; m++) {
        int row = wr + m * 16 + lr;
        af[m] = *(const bf16x8*)&ldsA[row * 64 + (ke ^ ((row & 7) << 3))];
      }
#pragma unroll
      for (int n = 0; n < 2; n++) {
        int row = wc + n * 16 + lr;
        bfr[n] = *(const bf16x8*)&ldsB[row * 64 + (ke ^ ((row & 7) << 3))];
      }
#pragma unroll
      for (int m = 0; m < 4; m++)
#pragma unroll
        for (int n = 0; n < 2; n++)
          acc[m][n] = __builtin_amdgcn_mfma_f32_16x16x32_bf16(af[m], bfr[n],
                                                              acc[m][n], 0, 0, 0);
    }
    __syncthreads();
  }
#pragma unroll
  for (int m = 0; m < 4; m++)
#pragma unroll
    for (int n = 0; n < 2; n++)
#pragma unroll
      for (int r = 0; r < 4; r++) {
        int gr = arow0 + wr + m * 16 + lg * 4 + r;
        int gc = bcol0 + wc + n * 16 + lr;
        out[(size_t)gr * 1024 + gc] = acc[m][n][r];
      }
}

extern "C" void kernel_launch(void* const* d_in, const int* in_sizes, int n_in,
                              void* d_out, int out_size, void* d_ws, size_t ws_size,
                              hipStream_t stream) {
  const float* q  = (const float*)d_in[0];
  const float* k  = (const float*)d_in[1];
  const float* v  = (const float*)d_in[2];
  const float* wq = (const float*)d_in[3];
  const float* wk = (const float*)d_in[4];
  const float* wv = (const float*)d_in[5];
  const float* wo = (const float*)d_in[6];
  float* out = (float*)d_out;
  char* ws = (char*)d_ws;

  u16* WT = (u16*)ws;                                    // [4][1024][1024]
  u16* Qh = (u16*)(ws + (size_t)32 * 1024 * 1024);       // [32][2048][64]
  u16* Kh = (u16*)(ws + (size_t)40 * 1024 * 1024);       // [32][2048][64]
  u16* Vt = (u16*)(ws + (size_t)48 * 1024 * 1024);       // [32][64][2048]
  u16* Ob = (u16*)(ws + (size_t)56 * 1024 * 1024);       // [4096][1024]

  wtrans_kernel<<<dim3(32, 32, 4), 256, 0, stream>>>(wq, wk, wv, wo, WT);
  proj_kernel<<<dim3(768), 256, 0, stream>>>(q, k, v, WT, Qh, Kh, Vt);
  attn_kernel<<<dim3(512), 512, 0, stream>>>(Qh, Kh, Vt, Ob);
  outproj_kernel<<<dim3(512), 256, 0, stream>>>(Ob, WT + (size_t)3 * 1024 * 1024, out);
}